// Round 12
// baseline (401.008 us; speedup 1.0000x reference)
//
#include <hip/hip_runtime.h>
#include <stdint.h>
#include <math.h>

#define DIM 1536
#define SEQ 4096
#define HEADS 12
#define HD 128

typedef __bf16 bf16x8 __attribute__((ext_vector_type(8)));
typedef float f32x4 __attribute__((ext_vector_type(4)));

typedef __attribute__((address_space(1))) void gas_void;
typedef __attribute__((address_space(3))) void las_void;

__device__ __forceinline__ float b2f(unsigned short u) {
  union { unsigned int i; float f; } x; x.i = ((unsigned int)u) << 16; return x.f;
}
__device__ __forceinline__ unsigned short f2b(float f) {
  union { float f; unsigned int i; } x; x.f = f;
  unsigned int u = x.i;
  unsigned int r = (u + 0x7fffu + ((u >> 16) & 1u)) >> 16;  // RNE
  return (unsigned short)r;
}
// async global->LDS 16B: LDS placement is wave-uniform base + lane*16
__device__ __forceinline__ void gll16(const unsigned short* g, unsigned short* l) {
  __builtin_amdgcn_global_load_lds((gas_void*)g, (las_void*)l, 16, 0, 0);
}
// packed f32x2 -> bf16x2 (RNE), single VALU op
__device__ __forceinline__ void cvtpk(unsigned int& d, float a, float b) {
  asm("v_cvt_pk_bf16_f32 %0, %1, %2" : "=v"(d) : "v"(a), "v"(b));
}
// after: a = {a[0:31], b[0:31]}, b = {a[32:63], b[32:63]}
__device__ __forceinline__ void pl32(unsigned int& a, unsigned int& b) {
  asm("v_permlane32_swap_b32 %0, %1" : "+v"(a), "+v"(b));
}
// after: a = {a[0:15], b[0:15], a[32:47], b[32:47]}, b = {a[16:31], b[16:31], a[48:63], b[48:63]}
__device__ __forceinline__ void pl16(unsigned int& a, unsigned int& b) {
  asm("v_permlane16_swap_b32 %0, %1" : "+v"(a), "+v"(b));
}
// raw 2^x (log2e folded into q upstream)
__device__ __forceinline__ float fexp2(float x) { return __builtin_amdgcn_exp2f(x); }

// ---------------- dtype detector: flag=0 bf16 inputs, flag=1 fp32 inputs
// (only launched when host can't resolve dtype from in_sizes)
__global__ void detect_kernel(const unsigned int* __restrict__ xw, int* flag) {
  __shared__ int cnt;
  if (threadIdx.x == 0) cnt = 0;
  __syncthreads();
  int local = 0;
  for (int i = threadIdx.x; i < 1024; i += 256) {
    unsigned int e = (xw[i] >> 7) & 0xFFu;
    if (e >= 110u && e <= 140u) local++;
  }
  atomicAdd(&cnt, local);
  __syncthreads();
  if (threadIdx.x == 0) *flag = (cnt > 512) ? 0 : 1;
}

// merged big converts, 4 elems/thread: y=0 -> x (n4 = NX/4), y=1..4 -> W.
// dtk >= 0: dtype known on host (0 bf16 / 1 f32); dtk < 0: read device flag.
__global__ void convert_big_kernel(const void* sx, const void* s0, const void* s1,
                                   const void* s2, const void* s3,
                                   unsigned short* dx, unsigned short* d0,
                                   unsigned short* d1, unsigned short* d2,
                                   unsigned short* d3,
                                   int nx4, int nw4, int dtk,
                                   const int* __restrict__ flag) {
  const void* s; unsigned short* d; int n4;
  switch (blockIdx.y) {
    case 0: s = sx; d = dx; n4 = nx4; break;
    case 1: s = s0; d = d0; n4 = nw4; break;
    case 2: s = s1; d = d1; n4 = nw4; break;
    case 3: s = s2; d = d2; n4 = nw4; break;
    default: s = s3; d = d3; n4 = nw4; break;
  }
  int f = (dtk >= 0) ? dtk : *flag;
  for (int i = blockIdx.x * blockDim.x + threadIdx.x; i < n4; i += gridDim.x * blockDim.x) {
    if (f) {
      float4 v = ((const float4*)s)[i];
      union { unsigned short h[4]; uint2 u; } pk;
      pk.h[0] = f2b(v.x); pk.h[1] = f2b(v.y); pk.h[2] = f2b(v.z); pk.h[3] = f2b(v.w);
      ((uint2*)d)[i] = pk.u;
    } else {
      ((uint2*)d)[i] = ((const uint2*)s)[i];
    }
  }
}

// merged small converts: y=0..5 -> bias/gain bf16 vectors (n=NB);
// y=6 -> freqs {cos,sin} float2 table (n=NF).
__global__ void convert_small_kernel(const void* s0, const void* s1, const void* s2,
                                     const void* s3, const void* s4, const void* s5,
                                     const void* sf,
                                     unsigned short* d0, unsigned short* d1,
                                     unsigned short* d2, unsigned short* d3,
                                     unsigned short* d4, unsigned short* d5,
                                     float2* df, int nb, int nf, int dtk,
                                     const int* __restrict__ flag) {
  int f = (dtk >= 0) ? dtk : *flag;
  if (blockIdx.y == 6) {
    for (int i = blockIdx.x * blockDim.x + threadIdx.x; i < nf; i += gridDim.x * blockDim.x) {
      float a = f ? ((const float*)sf)[i] : b2f(((const unsigned short*)sf)[i]);
      float sn, cs;
      __sincosf(a, &sn, &cs);
      df[i] = make_float2(cs, sn);
    }
    return;
  }
  const void* s; unsigned short* d;
  switch (blockIdx.y) {
    case 0: s = s0; d = d0; break;
    case 1: s = s1; d = d1; break;
    case 2: s = s2; d = d2; break;
    case 3: s = s3; d = d3; break;
    case 4: s = s4; d = d4; break;
    default: s = s5; d = d5; break;
  }
  for (int i = blockIdx.x * blockDim.x + threadIdx.x; i < nb; i += gridDim.x * blockDim.x)
    d[i] = f ? f2b(((const float*)s)[i]) : ((const unsigned short*)s)[i];
}

__global__ void signal_kernel(float* out) { if (threadIdx.x == 0) out[0] = 999.0f; }

// ---------------- GEMM: C[M,N] = A[M,K] @ W[N,K]^T + bias, bf16 in, fp32 acc
// BK=64, gll16 staging with both-sides XOR swizzle (rule #21).
template<int BM>
__device__ __forceinline__ void gemm_bt_body(
    const unsigned short* __restrict__ A,
    const unsigned short* __restrict__ W,
    const unsigned short* __restrict__ bias,
    unsigned short* __restrict__ Cb, float* __restrict__ Cf, int fmt, int vmode,
    int K, int N, int bx, int by)
{
  constexpr int BK = 64;               // shorts per row
  constexpr int MI = BM / 32;          // m-frags per wave (4 or 2)
  constexpr int ALINES = BM * BK * 2 / 4096;  // 4KB gll lines for A (4 or 2)
  __shared__ unsigned short As[BM * BK];
  __shared__ unsigned short Bs[128 * BK];
  const int t = threadIdx.x;
  const int wave = t >> 6, lane = t & 63;
  const int quad = lane >> 4, l16 = lane & 15;
  const int m0 = by * BM, n0 = bx * 128;
  const int wm = (wave >> 1) * (BM / 2), wn = (wave & 1) * 64;

  f32x4 acc[MI][4] = {};

  const int srow = t >> 3;
  const int scol = ((t & 7) ^ ((t >> 3) & 7)) * 8;
  const unsigned short* Ag = A + (size_t)(m0 + srow) * K + scol;
  const unsigned short* Wg = W + (size_t)(n0 + srow) * K + scol;

  for (int k0 = 0; k0 < K; k0 += BK) {
    __syncthreads();                 // prev iter's reads done
#pragma unroll
    for (int L = 0; L < ALINES; ++L)
      gll16(Ag + (size_t)L * 32 * K + k0, &As[L * 2048 + t * 8]);
#pragma unroll
    for (int L = 0; L < 4; ++L)
      gll16(Wg + (size_t)L * 32 * K + k0, &Bs[L * 2048 + t * 8]);
    __syncthreads();                 // drains vmcnt (gll complete) + visibility
#pragma unroll
    for (int c = 0; c < 2; ++c) {    // two K=32 chunks per staged tile
      bf16x8 af[MI], bfr[4];
#pragma unroll
      for (int i = 0; i < MI; ++i) {
        int row = wm + i * 16 + l16;
        af[i] = *(const bf16x8*)&As[row * 64 + ((c * 4 + quad) ^ (row & 7)) * 8];
      }
#pragma unroll
      for (int j = 0; j < 4; ++j) {
        int row = wn + j * 16 + l16;
        bfr[j] = *(const bf16x8*)&Bs[row * 64 + ((c * 4 + quad) ^ (row & 7)) * 8];
      }
#pragma unroll
      for (int i = 0; i < MI; ++i)
#pragma unroll
        for (int j = 0; j < 4; ++j)
          acc[i][j] = __builtin_amdgcn_mfma_f32_16x16x32_bf16(af[i], bfr[j], acc[i][j], 0, 0, 0);
    }
  }

#pragma unroll
  for (int i = 0; i < MI; ++i) {
    int row = m0 + wm + i * 16 + quad * 4;
#pragma unroll
    for (int j = 0; j < 4; ++j) {
      int col = n0 + wn + j * 16 + l16;
      float bv = b2f(bias[col]);
      if (vmode) {  // transposed: vt[col][row..row+3], 8B packed store
        union { unsigned short h4[4]; uint2 u; } pk;
#pragma unroll
        for (int r = 0; r < 4; ++r) pk.h4[r] = f2b(acc[i][j][r] + bv);
        *(uint2*)&Cb[(size_t)col * SEQ + row] = pk.u;
      } else {
#pragma unroll
        for (int r = 0; r < 4; ++r) {
          float v = acc[i][j][r] + bv;
          size_t idx = (size_t)(row + r) * N + col;
          if (fmt) Cf[idx] = v; else Cb[idx] = f2b(v);
        }
      }
    }
  }
}

// T1 XCD-chunked swizzle (bijective, nwg % 8 == 0).
// BM=64: grid 12 x 64 x 3 = 2304 blocks = 9/CU exactly balanced.
__global__ __launch_bounds__(256) void qkv_gemm_kernel(
    const unsigned short* __restrict__ x,
    const unsigned short* __restrict__ Wq, const unsigned short* __restrict__ bq,
    const unsigned short* __restrict__ Wk, const unsigned short* __restrict__ bk,
    const unsigned short* __restrict__ Wv, const unsigned short* __restrict__ bv,
    unsigned short* qb, unsigned short* kb, unsigned short* vt)
{
  const int flat = blockIdx.x + 12 * blockIdx.y + 768 * blockIdx.z;  // 2304
  const int swz = (flat & 7) * 288 + (flat >> 3);
  const int bz = swz / 768;
  const int rem = swz - bz * 768;
  const int by = rem / 12, bx = rem - by * 12;
  const unsigned short *W, *b; unsigned short* C; int vm = 0;
  if (bz == 0)      { W = Wq; b = bq; C = qb; }
  else if (bz == 1) { W = Wk; b = bk; C = kb; }
  else              { W = Wv; b = bv; C = vt; vm = 1; }
  gemm_bt_body<64>(x, W, b, C, nullptr, 0, vm, DIM, DIM, bx, by);
}

// BM=64: grid 12 x 64 = 768 blocks = 3/CU exactly
__global__ __launch_bounds__(256) void out_gemm_kernel(
    const unsigned short* __restrict__ ab, const unsigned short* __restrict__ Wo,
    const unsigned short* __restrict__ bo, void* out, int dtk,
    const int* __restrict__ flag)
{
  const int flat = blockIdx.x + 12 * blockIdx.y;     // 768
  const int swz = (flat & 7) * 96 + (flat >> 3);
  const int by = swz / 12, bx = swz - by * 12;
  int fmt = (dtk >= 0) ? dtk : *flag;
  gemm_bt_body<64>(ab, Wo, bo, (unsigned short*)out, (float*)out, fmt, 0,
                   DIM, DIM, bx, by);
}

// ---------------- RMSNorm + RoPE, in place
// q additionally pre-scaled by log2(e)/sqrt(d) so attn softmax uses raw 2^x.
__global__ __launch_bounds__(256) void norm_rope_kernel(
    unsigned short* __restrict__ qb, unsigned short* __restrict__ kb,
    const unsigned short* __restrict__ gq, const unsigned short* __restrict__ gk,
    const float2* __restrict__ csf)
{
  const int s = blockIdx.x;
  const int isq = (blockIdx.y == 0);
  unsigned short* row = (isq ? qb : kb) + (size_t)s * DIM;
  const unsigned short* g = (isq ? gq : gk);
  const int t = threadIdx.x;
  float ss = 0.f;
#pragma unroll
  for (int i = 0; i < 6; ++i) {
    float xv = b2f(row[t + 256 * i]);
    ss += xv * xv;
  }
#pragma unroll
  for (int off = 32; off > 0; off >>= 1) ss += __shfl_down(ss, off);
  __shared__ float red[4];
  if ((t & 63) == 0) red[t >> 6] = ss;
  __syncthreads();
  float tot = red[0] + red[1] + red[2] + red[3];
  float rinv = 1.0f / sqrtf(tot * (1.0f / DIM) + 1e-6f);
  if (isq) rinv *= 0.12751744900725559f;   // fold log2(e)/sqrt(128) into q
#pragma unroll
  for (int i = 0; i < 3; ++i) {
    int pg = t + 256 * i;
    int c0 = pg * 2;
    float x0 = b2f(row[c0]), x1 = b2f(row[c0 + 1]);
    float y0 = x0 * rinv * b2f(g[c0]);
    float y1 = x1 * rinv * b2f(g[c0 + 1]);
    float2 cs = csf[s * 64 + (pg & 63)];
    row[c0]     = f2b(y0 * cs.x - y1 * cs.y);
    row[c0 + 1] = f2b(y0 * cs.y + y1 * cs.x);
  }
}

// ---------------- Flash attention: 128 q/block, additive key-split (grid.z)
// R11 structure + K staged via global_load_lds into a DOUBLE-BUFFERED Ks:
// K_{t+1} gll16s issue at compute-start of tile t into Ks[(t+1)&1] and drain
// at the post-compute barrier (covered by ~1400cy of MFMA/VALU) -- same
// latency hiding as the old reg-prefetch, but deletes 4 global loads +
// 4 ds_write_b128 per thread per tile (-10% LDS-pipe issues) and 16 VGPRs.
// Geometry ([64][128], row=L*16+t>>4, blk=t&15, src pre-swizzle ^(row&7))
// hardware-validated in R6. V stays reg-staged (T14).
__global__ __launch_bounds__(256) void attn_kernel(
    const unsigned short* __restrict__ qb,
    const unsigned short* __restrict__ kb,
    const unsigned short* __restrict__ vt,   // [DIM][SEQ] transposed V
    float* __restrict__ op,                  // [nz][SEQ][DIM] partial O
    float* __restrict__ lp,                  // [nz][HEADS][SEQ] partial L
    int seg, int nwg)                        // keys per z-slice; total blocks
{
  __shared__ unsigned short Ks[2][64 * 128];   // [key][d] x2, swizzled
  __shared__ unsigned short Vs[128 * 64];      // [d][key], swizzled

  const int t = threadIdx.x;
  const int wave = t >> 6, lane = t & 63;
  const int quad = lane >> 4, l16 = lane & 15;

  // T1 bijective XCD chunk remap (nwg % 8 == 0): x fastest in flat order.
  const int flat = blockIdx.x + (gridDim.x) * (blockIdx.y + HEADS * blockIdx.z);
  const int swz = (flat & 7) * (nwg >> 3) + (flat >> 3);
  const int bx = swz & 31;                  // gridDim.x = 32
  const int rem = swz >> 5;
  const int h = rem % HEADS;
  const int z = rem / HEADS;

  const int qbase = bx * 128 + wave * 32;   // 32 q rows per wave
  const int kc0 = z * seg;
  const int nt = seg >> 6;

  // Q frags (used as B operand in swapped QK^T): 2 m-tiles x 4 k-groups
  bf16x8 qf[2][4];
#pragma unroll
  for (int mt = 0; mt < 2; ++mt)
#pragma unroll
    for (int kk = 0; kk < 4; ++kk)
      qf[mt][kk] = *(const bf16x8*)(qb + (size_t)(qbase + mt * 16 + l16) * DIM
                                    + h * HD + kk * 32 + quad * 8);

  f32x4 o[2][8] = {};
  float Lr[2] = {};

  // K gll16 staging for [64][128]: 4KB line L covers rows L*16+(t>>4),
  // phys 16B block t&15; source block pre-swizzled ^(row&7) so the read
  // XOR (kk*4+quad)^(row&7) recovers linear data (rule #21 involution).
  const int sK = t >> 4;
  const int cK = (t & 15) ^ (sK & 7);
  const unsigned short* Kg = kb + (size_t)sK * DIM + h * HD + cK * 8;

  // V reg staging: 4x16B per thread
  const int vd = t >> 1, vblk = (t & 1) * 4;
  const unsigned short* vbase = vt + ((size_t)h * HD + vd) * SEQ + vblk * 8;

  uint4 vr0, vr1, vr2, vr3;

  // prologue: K_0 -> Ks[0] (gll16), V_0 -> regs
#pragma unroll
  for (int L = 0; L < 4; ++L)
    gll16(Kg + (size_t)(kc0 + L * 16) * DIM, &Ks[0][L * 2048 + t * 8]);
  {
    const unsigned short* sv = vbase + kc0;
    vr0 = *(const uint4*)(sv);
    vr1 = *(const uint4*)(sv + 8);
    vr2 = *(const uint4*)(sv + 16);
    vr3 = *(const uint4*)(sv + 24);
  }
  __syncthreads();           // drains K_0 gll16
  {  // write V_0 [128 d][64 key], block swizzle
    unsigned short* dst = &Vs[vd * 64];
    const int sw = vd & 7;
    *(uint4*)(dst + ((vblk + 0) ^ sw) * 8) = vr0;
    *(uint4*)(dst + ((vblk + 1) ^ sw) * 8) = vr1;
    *(uint4*)(dst + ((vblk + 2) ^ sw) * 8) = vr2;
    *(uint4*)(dst + ((vblk + 3) ^ sw) * 8) = vr3;
  }
  __syncthreads();           // Vs + Ks[0] visible

  for (int it = 0; it < nt; ++it) {
    const int cur = it & 1;
    int nkc = kc0 + (it + 1) * 64;
    if (it + 1 >= nt) nkc = kc0 + it * 64;   // clamp: L2-hot re-read
    // issue next-tile staging FIRST: K_{t+1} -> back buffer (drains at the
    // post-compute barrier), V_{t+1} -> regs (consumed after that barrier)
#pragma unroll
    for (int L = 0; L < 4; ++L)
      gll16(Kg + (size_t)(nkc + L * 16) * DIM, &Ks[cur ^ 1][L * 2048 + t * 8]);
    {
      const unsigned short* sv = vbase + nkc;
      vr0 = *(const uint4*)(sv);
      vr1 = *(const uint4*)(sv + 8);
      vr2 = *(const uint4*)(sv + 16);
      vr3 = *(const uint4*)(sv + 24);
    }

    const unsigned short* ks = &Ks[cur][0];

    // S^T = K @ Q^T (swapped operands): C[key][q], lane: q=mt*16+l16 (col),
    // key=j*16+quad*4+r (row).
    f32x4 sc[2][4] = {};
    __builtin_amdgcn_s_setprio(1);
#pragma unroll
    for (int kk = 0; kk < 4; ++kk) {
#pragma unroll
      for (int j = 0; j < 4; ++j) {
        int row = j * 16 + l16;
        bf16x8 kf = *(const bf16x8*)&ks[row * 128 + ((kk * 4 + quad) ^ (row & 7)) * 8];
        sc[0][j] = __builtin_amdgcn_mfma_f32_16x16x32_bf16(kf, qf[0][kk], sc[0][j], 0, 0, 0);
        sc[1][j] = __builtin_amdgcn_mfma_f32_16x16x32_bf16(kf, qf[1][kk], sc[1][j], 0, 0, 0);
      }
    }
    __builtin_amdgcn_s_setprio(0);

    // fixed-max softmax in registers (scores bounded: q,k RMS-normalized).
    // q carries log2e -> raw v_exp_f32. wlo[mt][j] = keys j*16+quad*4+{0,1}.
    unsigned int wlo[2][4], whi[2][4];
#pragma unroll
    for (int mt = 0; mt < 2; ++mt) {
      float ls = 0.f;
#pragma unroll
      for (int j = 0; j < 4; ++j) {
        float p0 = fexp2(sc[mt][j][0]);
        float p1 = fexp2(sc[mt][j][1]);
        float p2 = fexp2(sc[mt][j][2]);
        float p3 = fexp2(sc[mt][j][3]);
        ls += (p0 + p1) + (p2 + p3);
        cvtpk(wlo[mt][j], p0, p1);
        cvtpk(whi[mt][j], p2, p3);
      }
      Lr[mt] += ls;
    }

    // permlane double-swap -> PV A-frags in registers.
    bf16x8 pf[2][2];
#pragma unroll
    for (int mt = 0; mt < 2; ++mt)
#pragma unroll
      for (int kk2 = 0; kk2 < 2; ++kk2) {
        unsigned int ul = wlo[mt][kk2 * 2], vl = wlo[mt][kk2 * 2 + 1];
        unsigned int uh = whi[mt][kk2 * 2], vh = whi[mt][kk2 * 2 + 1];
        pl32(ul, vl); pl16(ul, vl);
        pl32(uh, vh); pl16(uh, vh);
        union { unsigned int w[4]; bf16x8 v; } u;
        u.w[0] = ul; u.w[1] = uh; u.w[2] = vl; u.w[3] = vh;
        pf[mt][kk2] = u.v;
      }

    // O += P @ V : each vf read feeds both m-tiles
    __builtin_amdgcn_s_setprio(1);
#pragma unroll
    for (int kk2 = 0; kk2 < 2; ++kk2) {
#pragma unroll
      for (int j2 = 0; j2 < 8; ++j2) {
        bf16x8 vf = *(const bf16x8*)&Vs[(j2 * 16 + l16) * 64
                                        + ((kk2 * 4 + quad) ^ (l16 & 7)) * 8];
        o[0][j2] = __builtin_amdgcn_mfma_f32_16x16x32_bf16(pf[0][kk2], vf, o[0][j2], 0, 0, 0);
        o[1][j2] = __builtin_amdgcn_mfma_f32_16x16x32_bf16(pf[1][kk2], vf, o[1][j2], 0, 0, 0);
      }
    }
    __builtin_amdgcn_s_setprio(0);

    __syncthreads();   // drains K_{t+1} gll16; orders this tile's Ks/Vs reads
    {  // write V_{t+1} (regs landed; waitcnt inserted by compiler at use)
      unsigned short* dst = &Vs[vd * 64];
      const int sw = vd & 7;
      *(uint4*)(dst + ((vblk + 0) ^ sw) * 8) = vr0;
      *(uint4*)(dst + ((vblk + 1) ^ sw) * 8) = vr1;
      *(uint4*)(dst + ((vblk + 2) ^ sw) * 8) = vr2;
      *(uint4*)(dst + ((vblk + 3) ^ sw) * 8) = vr3;
    }
    __syncthreads();   // Vs + Ks[(t+1)&1] visible for next iter
  }

  // write partial L (quads hold disjoint key subsets -> reduce across quads)
  float* opz = op + (size_t)z * SEQ * DIM;
  float* lpz = lp + (size_t)z * HEADS * SEQ + (size_t)h * SEQ;
#pragma unroll
  for (int mt = 0; mt < 2; ++mt) {
    float L = Lr[mt];
    L += __shfl_xor(L, 16);
    L += __shfl_xor(L, 32);
    if (lane < 16) lpz[qbase + mt * 16 + l16] = L;
  }
#pragma unroll
  for (int mt = 0; mt < 2; ++mt) {
#pragma unroll
    for (int j2 = 0; j2 < 8; ++j2) {
      int col = h * HD + j2 * 16 + l16;
#pragma unroll
      for (int r = 0; r < 4; ++r) {
        int row = qbase + mt * 16 + quad * 4 + r;
        opz[(size_t)row * DIM + col] = o[mt][j2][r];
      }
    }
  }
}

// combine nz key-slices: ab = (sum O_z) / (sum L_z), cast to bf16.
__global__ __launch_bounds__(256) void combine_kernel(
    const float* __restrict__ op, const float* __restrict__ lp,
    unsigned short* __restrict__ ab, int nz)
{
  int idx4 = blockIdx.x * 256 + threadIdx.x;      // over SEQ*DIM/4
  int idx = idx4 * 4;
  int row = idx / DIM, col = idx - row * DIM;
  int h = col >> 7;
  float4 o = make_float4(0.f, 0.f, 0.f, 0.f);
  float l = 0.f;
  for (int z = 0; z < nz; ++z) {
    float4 v = *(const float4*)(op + (size_t)z * SEQ * DIM + idx);
    o.x += v.x; o.y += v.y; o.z += v.z; o.w += v.w;
    l += lp[(size_t)z * HEADS * SEQ + (size_t)h * SEQ + row];
  }
  float inv = 1.0f / l;
  union { unsigned short h4[4]; uint2 u; } pk;
  pk.h4[0] = f2b(o.x * inv);
  pk.h4[1] = f2b(o.y * inv);
  pk.h4[2] = f2b(o.z * inv);
  pk.h4[3] = f2b(o.w * inv);
  *(uint2*)&ab[idx] = pk.u;
}

extern "C" void kernel_launch(void* const* d_in, const int* in_sizes, int n_in,
                              void* d_out, int out_size, void* d_ws, size_t ws_size,
                              hipStream_t stream) {
  const int NX = SEQ * DIM, NW = DIM * DIM, NB = DIM, NF = SEQ * 64;

  char* w = (char*)d_ws;
  size_t off = 0;
  int* flag = (int*)(w + off);              off += 256;
  unsigned short* xb  = (unsigned short*)(w + off); off += (size_t)NX * 2;
  unsigned short* Wqb = (unsigned short*)(w + off); off += (size_t)NW * 2;
  unsigned short* Wkb = (unsigned short*)(w + off); off += (size_t)NW * 2;
  unsigned short* Wvb = (unsigned short*)(w + off); off += (size_t)NW * 2;
  unsigned short* Wob = (unsigned short*)(w + off); off += (size_t)NW * 2;
  unsigned short* bqb = (unsigned short*)(w + off); off += 4096;
  unsigned short* bkb = (unsigned short*)(w + off); off += 4096;
  unsigned short* bvb = (unsigned short*)(w + off); off += 4096;
  unsigned short* bob = (unsigned short*)(w + off); off += 4096;
  unsigned short* gqb = (unsigned short*)(w + off); off += 4096;
  unsigned short* gkb = (unsigned short*)(w + off); off += 4096;
  float2* freqcs = (float2*)(w + off);      off += (size_t)NF * 8;
  unsigned short* qb = (unsigned short*)(w + off); off += (size_t)NX * 2;
  unsigned short* kb = (unsigned short*)(w + off); off += (size_t)NX * 2;
  unsigned short* vt = (unsigned short*)(w + off); off += (size_t)NX * 2;
  unsigned short* ab = (unsigned short*)(w + off); off += (size_t)NX * 2;
  float* op = (float*)(w + off);            // nz * NX floats
  float* lp;

  // key-split factor nz=2: grid 768 blocks = 3 resident blocks/CU x 256 CUs.
  int nz = 2;
  size_t need2 = off + (size_t)2 * NX * 4 + (size_t)2 * HEADS * SEQ * 4;
  if (ws_size < need2) {
    signal_kernel<<<1, 64, 0, stream>>>((float*)d_out);
    return;
  }
  lp = (float*)(w + off + (size_t)nz * NX * 4);

  // Host-side dtype resolution from in_sizes (strict, with safe fallback).
  int dt = -1;
  if ((long long)in_sizes[0] == (long long)NX * 2 &&
      (long long)in_sizes[2] == (long long)NW * 2) dt = 0;
  else if ((long long)in_sizes[0] == (long long)NX * 4 &&
           (long long)in_sizes[2] == (long long)NW * 4) dt = 1;

  if (dt < 0)
    detect_kernel<<<1, 256, 0, stream>>>((const unsigned int*)d_in[0], flag);

  const int CT = 256;
  auto cgrid = [](int n) { int g = (n + 255) / 256; return g > 4096 ? 4096 : g; };

  // bf16-known: inputs are readable as bf16 directly -- skip the big copy.
  const unsigned short* xg  = xb;
  const unsigned short* Wqg = Wqb, *Wkg = Wkb, *Wvg = Wvb, *Wog = Wob;
  const unsigned short* bqg = bqb, *bkg = bkb, *bvg = bvb, *bog = bob;
  const unsigned short* gqg = gqb, *gkg = gkb;
  if (dt == 0) {
    xg  = (const unsigned short*)d_in[0];
    Wqg = (const unsigned short*)d_in[2];
    Wkg = (const unsigned short*)d_in[4];
    Wvg = (const unsigned short*)d_in[6];
    Wog = (const unsigned short*)d_in[8];
    bqg = (const unsigned short*)d_in[3];
    bkg = (const unsigned short*)d_in[5];
    bvg = (const unsigned short*)d_in[7];
    bog = (const unsigned short*)d_in[9];
    gqg = (const unsigned short*)d_in[10];
    gkg = (const unsigned short*)d_in[11];
  } else {
    convert_big_kernel<<<dim3(cgrid(NW / 4), 5), CT, 0, stream>>>(
        d_in[0], d_in[2], d_in[4], d_in[6], d_in[8],
        xb, Wqb, Wkb, Wvb, Wob, NX / 4, NW / 4, dt, flag);
  }
  convert_small_kernel<<<dim3(cgrid(NF), 7), CT, 0, stream>>>(
      d_in[3], d_in[5], d_in[7], d_in[9], d_in[10], d_in[11], d_in[1],
      bqb, bkb, bvb, bob, gqb, gkb, freqcs, NB, NF, dt, flag);

  qkv_gemm_kernel<<<dim3(DIM / 128, SEQ / 64, 3), 256, 0, stream>>>(
      xg, Wqg, bqg, Wkg, bkg, Wvg, bvg, qb, kb, vt);
  norm_rope_kernel<<<dim3(SEQ, 2), 256, 0, stream>>>(qb, kb, gqg, gkg, freqcs);
  attn_kernel<<<dim3(SEQ / 128, HEADS, nz), 256, 0, stream>>>(
      qb, kb, vt, op, lp, SEQ / nz, (SEQ / 128) * HEADS * nz);
  combine_kernel<<<NX / 1024, 256, 0, stream>>>(op, lp, ab, nz);
  out_gemm_kernel<<<dim3(DIM / 128, SEQ / 64), 256, 0, stream>>>(
      ab, Wog, bog, d_out, dt, flag);
}

// Round 13
// 383.517 us; speedup vs baseline: 1.0456x; 1.0456x over previous
//
#include <hip/hip_runtime.h>
#include <stdint.h>
#include <math.h>

#define DIM 1536
#define SEQ 4096
#define HEADS 12
#define HD 128

typedef __bf16 bf16x8 __attribute__((ext_vector_type(8)));
typedef float f32x4 __attribute__((ext_vector_type(4)));

typedef __attribute__((address_space(1))) void gas_void;
typedef __attribute__((address_space(3))) void las_void;

__device__ __forceinline__ float b2f(unsigned short u) {
  union { unsigned int i; float f; } x; x.i = ((unsigned int)u) << 16; return x.f;
}
__device__ __forceinline__ unsigned short f2b(float f) {
  union { float f; unsigned int i; } x; x.f = f;
  unsigned int u = x.i;
  unsigned int r = (u + 0x7fffu + ((u >> 16) & 1u)) >> 16;  // RNE
  return (unsigned short)r;
}
// async global->LDS 16B: LDS placement is wave-uniform base + lane*16
__device__ __forceinline__ void gll16(const unsigned short* g, unsigned short* l) {
  __builtin_amdgcn_global_load_lds((gas_void*)g, (las_void*)l, 16, 0, 0);
}
// packed f32x2 -> bf16x2 (RNE), single VALU op
__device__ __forceinline__ void cvtpk(unsigned int& d, float a, float b) {
  asm("v_cvt_pk_bf16_f32 %0, %1, %2" : "=v"(d) : "v"(a), "v"(b));
}
// after: a = {a[0:31], b[0:31]}, b = {a[32:63], b[32:63]}
__device__ __forceinline__ void pl32(unsigned int& a, unsigned int& b) {
  asm("v_permlane32_swap_b32 %0, %1" : "+v"(a), "+v"(b));
}
// after: a = {a[0:15], b[0:15], a[32:47], b[32:47]}, b = {a[16:31], b[16:31], a[48:63], b[48:63]}
__device__ __forceinline__ void pl16(unsigned int& a, unsigned int& b) {
  asm("v_permlane16_swap_b32 %0, %1" : "+v"(a), "+v"(b));
}
// raw 2^x (log2e folded into q upstream)
__device__ __forceinline__ float fexp2(float x) { return __builtin_amdgcn_exp2f(x); }

// ---------------- dtype detector: flag=0 bf16 inputs, flag=1 fp32 inputs
// (only launched when host can't resolve dtype from in_sizes)
__global__ void detect_kernel(const unsigned int* __restrict__ xw, int* flag) {
  __shared__ int cnt;
  if (threadIdx.x == 0) cnt = 0;
  __syncthreads();
  int local = 0;
  for (int i = threadIdx.x; i < 1024; i += 256) {
    unsigned int e = (xw[i] >> 7) & 0xFFu;
    if (e >= 110u && e <= 140u) local++;
  }
  atomicAdd(&cnt, local);
  __syncthreads();
  if (threadIdx.x == 0) *flag = (cnt > 512) ? 0 : 1;
}

// merged big converts, 4 elems/thread: y=0 -> x (n4 = NX/4), y=1..4 -> W.
// dtk >= 0: dtype known on host (0 bf16 / 1 f32); dtk < 0: read device flag.
__global__ void convert_big_kernel(const void* sx, const void* s0, const void* s1,
                                   const void* s2, const void* s3,
                                   unsigned short* dx, unsigned short* d0,
                                   unsigned short* d1, unsigned short* d2,
                                   unsigned short* d3,
                                   int nx4, int nw4, int dtk,
                                   const int* __restrict__ flag) {
  const void* s; unsigned short* d; int n4;
  switch (blockIdx.y) {
    case 0: s = sx; d = dx; n4 = nx4; break;
    case 1: s = s0; d = d0; n4 = nw4; break;
    case 2: s = s1; d = d1; n4 = nw4; break;
    case 3: s = s2; d = d2; n4 = nw4; break;
    default: s = s3; d = d3; n4 = nw4; break;
  }
  int f = (dtk >= 0) ? dtk : *flag;
  for (int i = blockIdx.x * blockDim.x + threadIdx.x; i < n4; i += gridDim.x * blockDim.x) {
    if (f) {
      float4 v = ((const float4*)s)[i];
      union { unsigned short h[4]; uint2 u; } pk;
      pk.h[0] = f2b(v.x); pk.h[1] = f2b(v.y); pk.h[2] = f2b(v.z); pk.h[3] = f2b(v.w);
      ((uint2*)d)[i] = pk.u;
    } else {
      ((uint2*)d)[i] = ((const uint2*)s)[i];
    }
  }
}

// merged small converts: y=0..5 -> bias/gain bf16 vectors (n=NB);
// y=6 -> freqs {cos,sin} float2 table (n=NF).
__global__ void convert_small_kernel(const void* s0, const void* s1, const void* s2,
                                     const void* s3, const void* s4, const void* s5,
                                     const void* sf,
                                     unsigned short* d0, unsigned short* d1,
                                     unsigned short* d2, unsigned short* d3,
                                     unsigned short* d4, unsigned short* d5,
                                     float2* df, int nb, int nf, int dtk,
                                     const int* __restrict__ flag) {
  int f = (dtk >= 0) ? dtk : *flag;
  if (blockIdx.y == 6) {
    for (int i = blockIdx.x * blockDim.x + threadIdx.x; i < nf; i += gridDim.x * blockDim.x) {
      float a = f ? ((const float*)sf)[i] : b2f(((const unsigned short*)sf)[i]);
      float sn, cs;
      __sincosf(a, &sn, &cs);
      df[i] = make_float2(cs, sn);
    }
    return;
  }
  const void* s; unsigned short* d;
  switch (blockIdx.y) {
    case 0: s = s0; d = d0; break;
    case 1: s = s1; d = d1; break;
    case 2: s = s2; d = d2; break;
    case 3: s = s3; d = d3; break;
    case 4: s = s4; d = d4; break;
    default: s = s5; d = d5; break;
  }
  for (int i = blockIdx.x * blockDim.x + threadIdx.x; i < nb; i += gridDim.x * blockDim.x)
    d[i] = f ? f2b(((const float*)s)[i]) : ((const unsigned short*)s)[i];
}

__global__ void signal_kernel(float* out) { if (threadIdx.x == 0) out[0] = 999.0f; }

// ---------------- GEMM: C[M,N] = A[M,K] @ W[N,K]^T + bias, bf16 in, fp32 acc
// BK=64, gll16 staging with both-sides XOR swizzle (rule #21).
template<int BM>
__device__ __forceinline__ void gemm_bt_body(
    const unsigned short* __restrict__ A,
    const unsigned short* __restrict__ W,
    const unsigned short* __restrict__ bias,
    unsigned short* __restrict__ Cb, float* __restrict__ Cf, int fmt, int vmode,
    int K, int N, int bx, int by)
{
  constexpr int BK = 64;               // shorts per row
  constexpr int MI = BM / 32;          // m-frags per wave (4 or 2)
  constexpr int ALINES = BM * BK * 2 / 4096;  // 4KB gll lines for A (4 or 2)
  __shared__ unsigned short As[BM * BK];
  __shared__ unsigned short Bs[128 * BK];
  const int t = threadIdx.x;
  const int wave = t >> 6, lane = t & 63;
  const int quad = lane >> 4, l16 = lane & 15;
  const int m0 = by * BM, n0 = bx * 128;
  const int wm = (wave >> 1) * (BM / 2), wn = (wave & 1) * 64;

  f32x4 acc[MI][4] = {};

  const int srow = t >> 3;
  const int scol = ((t & 7) ^ ((t >> 3) & 7)) * 8;
  const unsigned short* Ag = A + (size_t)(m0 + srow) * K + scol;
  const unsigned short* Wg = W + (size_t)(n0 + srow) * K + scol;

  for (int k0 = 0; k0 < K; k0 += BK) {
    __syncthreads();                 // prev iter's reads done
#pragma unroll
    for (int L = 0; L < ALINES; ++L)
      gll16(Ag + (size_t)L * 32 * K + k0, &As[L * 2048 + t * 8]);
#pragma unroll
    for (int L = 0; L < 4; ++L)
      gll16(Wg + (size_t)L * 32 * K + k0, &Bs[L * 2048 + t * 8]);
    __syncthreads();                 // drains vmcnt (gll complete) + visibility
#pragma unroll
    for (int c = 0; c < 2; ++c) {    // two K=32 chunks per staged tile
      bf16x8 af[MI], bfr[4];
#pragma unroll
      for (int i = 0; i < MI; ++i) {
        int row = wm + i * 16 + l16;
        af[i] = *(const bf16x8*)&As[row * 64 + ((c * 4 + quad) ^ (row & 7)) * 8];
      }
#pragma unroll
      for (int j = 0; j < 4; ++j) {
        int row = wn + j * 16 + l16;
        bfr[j] = *(const bf16x8*)&Bs[row * 64 + ((c * 4 + quad) ^ (row & 7)) * 8];
      }
#pragma unroll
      for (int i = 0; i < MI; ++i)
#pragma unroll
        for (int j = 0; j < 4; ++j)
          acc[i][j] = __builtin_amdgcn_mfma_f32_16x16x32_bf16(af[i], bfr[j], acc[i][j], 0, 0, 0);
    }
  }

#pragma unroll
  for (int i = 0; i < MI; ++i) {
    int row = m0 + wm + i * 16 + quad * 4;
#pragma unroll
    for (int j = 0; j < 4; ++j) {
      int col = n0 + wn + j * 16 + l16;
      float bv = b2f(bias[col]);
      if (vmode) {  // transposed: vt[col][row..row+3], 8B packed store
        union { unsigned short h4[4]; uint2 u; } pk;
#pragma unroll
        for (int r = 0; r < 4; ++r) pk.h4[r] = f2b(acc[i][j][r] + bv);
        *(uint2*)&Cb[(size_t)col * SEQ + row] = pk.u;
      } else {
#pragma unroll
        for (int r = 0; r < 4; ++r) {
          float v = acc[i][j][r] + bv;
          size_t idx = (size_t)(row + r) * N + col;
          if (fmt) Cf[idx] = v; else Cb[idx] = f2b(v);
        }
      }
    }
  }
}

// T1 XCD-chunked swizzle (bijective, nwg % 8 == 0).
// BM=64: grid 12 x 64 x 3 = 2304 blocks = 9/CU exactly balanced.
__global__ __launch_bounds__(256) void qkv_gemm_kernel(
    const unsigned short* __restrict__ x,
    const unsigned short* __restrict__ Wq, const unsigned short* __restrict__ bq,
    const unsigned short* __restrict__ Wk, const unsigned short* __restrict__ bk,
    const unsigned short* __restrict__ Wv, const unsigned short* __restrict__ bv,
    unsigned short* qb, unsigned short* kb, unsigned short* vt)
{
  const int flat = blockIdx.x + 12 * blockIdx.y + 768 * blockIdx.z;  // 2304
  const int swz = (flat & 7) * 288 + (flat >> 3);
  const int bz = swz / 768;
  const int rem = swz - bz * 768;
  const int by = rem / 12, bx = rem - by * 12;
  const unsigned short *W, *b; unsigned short* C; int vm = 0;
  if (bz == 0)      { W = Wq; b = bq; C = qb; }
  else if (bz == 1) { W = Wk; b = bk; C = kb; }
  else              { W = Wv; b = bv; C = vt; vm = 1; }
  gemm_bt_body<64>(x, W, b, C, nullptr, 0, vm, DIM, DIM, bx, by);
}

// BM=64: grid 12 x 64 = 768 blocks = 3/CU exactly
__global__ __launch_bounds__(256) void out_gemm_kernel(
    const unsigned short* __restrict__ ab, const unsigned short* __restrict__ Wo,
    const unsigned short* __restrict__ bo, void* out, int dtk,
    const int* __restrict__ flag)
{
  const int flat = blockIdx.x + 12 * blockIdx.y;     // 768
  const int swz = (flat & 7) * 96 + (flat >> 3);
  const int by = swz / 12, bx = swz - by * 12;
  int fmt = (dtk >= 0) ? dtk : *flag;
  gemm_bt_body<64>(ab, Wo, bo, (unsigned short*)out, (float*)out, fmt, 0,
                   DIM, DIM, bx, by);
}

// ---------------- RMSNorm + RoPE, in place
// q additionally pre-scaled by log2(e)/sqrt(d) so attn softmax uses raw 2^x.
__global__ __launch_bounds__(256) void norm_rope_kernel(
    unsigned short* __restrict__ qb, unsigned short* __restrict__ kb,
    const unsigned short* __restrict__ gq, const unsigned short* __restrict__ gk,
    const float2* __restrict__ csf)
{
  const int s = blockIdx.x;
  const int isq = (blockIdx.y == 0);
  unsigned short* row = (isq ? qb : kb) + (size_t)s * DIM;
  const unsigned short* g = (isq ? gq : gk);
  const int t = threadIdx.x;
  float ss = 0.f;
#pragma unroll
  for (int i = 0; i < 6; ++i) {
    float xv = b2f(row[t + 256 * i]);
    ss += xv * xv;
  }
#pragma unroll
  for (int off = 32; off > 0; off >>= 1) ss += __shfl_down(ss, off);
  __shared__ float red[4];
  if ((t & 63) == 0) red[t >> 6] = ss;
  __syncthreads();
  float tot = red[0] + red[1] + red[2] + red[3];
  float rinv = 1.0f / sqrtf(tot * (1.0f / DIM) + 1e-6f);
  if (isq) rinv *= 0.12751744900725559f;   // fold log2(e)/sqrt(128) into q
#pragma unroll
  for (int i = 0; i < 3; ++i) {
    int pg = t + 256 * i;
    int c0 = pg * 2;
    float x0 = b2f(row[c0]), x1 = b2f(row[c0 + 1]);
    float y0 = x0 * rinv * b2f(g[c0]);
    float y1 = x1 * rinv * b2f(g[c0 + 1]);
    float2 cs = csf[s * 64 + (pg & 63)];
    row[c0]     = f2b(y0 * cs.x - y1 * cs.y);
    row[c0 + 1] = f2b(y0 * cs.y + y1 * cs.x);
  }
}

// ---------------- Flash attention: 128 q/block, additive key-split (grid.z)
// R11 known-good (best measured: attn 148.3us): T14 async reg-prefetch of
// next K/V tile + T12 in-register softmax (swapped QK^T, cvt_pk + permlane
// double-swap, no P LDS round-trip) + T5 setprio + exp2-direct softmax +
// T1 XCD-chunked blockIdx swizzle (FETCH 108->24.6MB).
// Structural variants tried and REGRESSED -- do not reintroduce:
//  - T15 double-sc defer (R5/R6): spills at this register budget (VGPR->84,
//    FETCH 10x from scratch).
//  - K via global_load_lds + Ks dbuf (R12): post-compute barrier's implicit
//    vmcnt(0) drains the staging queue in lockstep (the m97 barrier-drain
//    stall); reg-staged K decouples load-landing from the barrier. 148->164us.
__global__ __launch_bounds__(256) void attn_kernel(
    const unsigned short* __restrict__ qb,
    const unsigned short* __restrict__ kb,
    const unsigned short* __restrict__ vt,   // [DIM][SEQ] transposed V
    float* __restrict__ op,                  // [nz][SEQ][DIM] partial O
    float* __restrict__ lp,                  // [nz][HEADS][SEQ] partial L
    int seg, int nwg)                        // keys per z-slice; total blocks
{
  __shared__ unsigned short Ks[64 * 128];      // [key][d], swizzled
  __shared__ unsigned short Vs[128 * 64];      // [d][key], swizzled

  const int t = threadIdx.x;
  const int wave = t >> 6, lane = t & 63;
  const int quad = lane >> 4, l16 = lane & 15;

  // T1 bijective XCD chunk remap (nwg % 8 == 0): x fastest in flat order.
  const int flat = blockIdx.x + (gridDim.x) * (blockIdx.y + HEADS * blockIdx.z);
  const int swz = (flat & 7) * (nwg >> 3) + (flat >> 3);
  const int bx = swz & 31;                  // gridDim.x = 32
  const int rem = swz >> 5;
  const int h = rem % HEADS;
  const int z = rem / HEADS;

  const int qbase = bx * 128 + wave * 32;   // 32 q rows per wave
  const int kc0 = z * seg;

  // Q frags (used as B operand in swapped QK^T): 2 m-tiles x 4 k-groups
  bf16x8 qf[2][4];
#pragma unroll
  for (int mt = 0; mt < 2; ++mt)
#pragma unroll
    for (int kk = 0; kk < 4; ++kk)
      qf[mt][kk] = *(const bf16x8*)(qb + (size_t)(qbase + mt * 16 + l16) * DIM
                                    + h * HD + kk * 32 + quad * 8);

  f32x4 o[2][8] = {};
  float Lr[2] = {};

  const int krow = t >> 2, kblk = (t & 3) * 4;   // K stage: 4x16B per thread
  const int vd = t >> 1,  vblk = (t & 1) * 4;    // V stage: 4x16B per thread

  const unsigned short* kbase = kb + (size_t)krow * DIM + h * HD + kblk * 8;
  const unsigned short* vbase = vt + ((size_t)h * HD + vd) * SEQ + vblk * 8;

  // prologue: prefetch first tile into regs
  uint4 kr0, kr1, kr2, kr3, vr0, vr1, vr2, vr3;
  {
    const unsigned short* s = kbase + (size_t)kc0 * DIM;
    kr0 = *(const uint4*)(s);
    kr1 = *(const uint4*)(s + 8);
    kr2 = *(const uint4*)(s + 16);
    kr3 = *(const uint4*)(s + 24);
    const unsigned short* sv = vbase + kc0;
    vr0 = *(const uint4*)(sv);
    vr1 = *(const uint4*)(sv + 8);
    vr2 = *(const uint4*)(sv + 16);
    vr3 = *(const uint4*)(sv + 24);
  }

  for (int kc = kc0; kc < kc0 + seg; kc += 64) {
    __syncthreads();     // prev tile's LDS reads done
    {  // write staged K regs [64][128] with block swizzle
      unsigned short* dst = &Ks[krow * 128];
      const int sw = krow & 7;
      *(uint4*)(dst + ((kblk + 0) ^ sw) * 8) = kr0;
      *(uint4*)(dst + ((kblk + 1) ^ sw) * 8) = kr1;
      *(uint4*)(dst + ((kblk + 2) ^ sw) * 8) = kr2;
      *(uint4*)(dst + ((kblk + 3) ^ sw) * 8) = kr3;
    }
    {  // write staged V regs [128 d][64 key], block swizzle
      unsigned short* dst = &Vs[vd * 64];
      const int sw = vd & 7;
      *(uint4*)(dst + ((vblk + 0) ^ sw) * 8) = vr0;
      *(uint4*)(dst + ((vblk + 1) ^ sw) * 8) = vr1;
      *(uint4*)(dst + ((vblk + 2) ^ sw) * 8) = vr2;
      *(uint4*)(dst + ((vblk + 3) ^ sw) * 8) = vr3;
    }
    __syncthreads();

    {  // prefetch next tile (clamped on last iter -> cheap L2-hot re-read)
      int nkc = kc + 64;
      if (nkc >= kc0 + seg) nkc = kc;
      const unsigned short* s = kbase + (size_t)nkc * DIM;
      kr0 = *(const uint4*)(s);
      kr1 = *(const uint4*)(s + 8);
      kr2 = *(const uint4*)(s + 16);
      kr3 = *(const uint4*)(s + 24);
      const unsigned short* sv = vbase + nkc;
      vr0 = *(const uint4*)(sv);
      vr1 = *(const uint4*)(sv + 8);
      vr2 = *(const uint4*)(sv + 16);
      vr3 = *(const uint4*)(sv + 24);
    }

    // S^T = K @ Q^T (swapped operands): C[key][q], lane: q=mt*16+l16 (col),
    // key=j*16+quad*4+r (row). Same kf/qf register data as unswapped.
    f32x4 sc[2][4] = {};
    __builtin_amdgcn_s_setprio(1);
#pragma unroll
    for (int kk = 0; kk < 4; ++kk) {
#pragma unroll
      for (int j = 0; j < 4; ++j) {
        int row = j * 16 + l16;
        bf16x8 kf = *(const bf16x8*)&Ks[row * 128 + ((kk * 4 + quad) ^ (row & 7)) * 8];
        sc[0][j] = __builtin_amdgcn_mfma_f32_16x16x32_bf16(kf, qf[0][kk], sc[0][j], 0, 0, 0);
        sc[1][j] = __builtin_amdgcn_mfma_f32_16x16x32_bf16(kf, qf[1][kk], sc[1][j], 0, 0, 0);
      }
    }
    __builtin_amdgcn_s_setprio(0);

    // fixed-max softmax in registers (scores bounded: q,k RMS-normalized).
    // q carries log2e -> raw v_exp_f32. wlo[mt][j] = keys j*16+quad*4+{0,1}.
    unsigned int wlo[2][4], whi[2][4];
#pragma unroll
    for (int mt = 0; mt < 2; ++mt) {
      float ls = 0.f;
#pragma unroll
      for (int j = 0; j < 4; ++j) {
        float p0 = fexp2(sc[mt][j][0]);
        float p1 = fexp2(sc[mt][j][1]);
        float p2 = fexp2(sc[mt][j][2]);
        float p3 = fexp2(sc[mt][j][3]);
        ls += (p0 + p1) + (p2 + p3);
        cvtpk(wlo[mt][j], p0, p1);
        cvtpk(whi[mt][j], p2, p3);
      }
      Lr[mt] += ls;
    }

    // permlane double-swap -> PV A-frags in registers.
    bf16x8 pf[2][2];
#pragma unroll
    for (int mt = 0; mt < 2; ++mt)
#pragma unroll
      for (int kk2 = 0; kk2 < 2; ++kk2) {
        unsigned int ul = wlo[mt][kk2 * 2], vl = wlo[mt][kk2 * 2 + 1];
        unsigned int uh = whi[mt][kk2 * 2], vh = whi[mt][kk2 * 2 + 1];
        pl32(ul, vl); pl16(ul, vl);
        pl32(uh, vh); pl16(uh, vh);
        union { unsigned int w[4]; bf16x8 v; } u;
        u.w[0] = ul; u.w[1] = uh; u.w[2] = vl; u.w[3] = vh;
        pf[mt][kk2] = u.v;
      }

    // O += P @ V : each vf read feeds both m-tiles
    __builtin_amdgcn_s_setprio(1);
#pragma unroll
    for (int kk2 = 0; kk2 < 2; ++kk2) {
#pragma unroll
      for (int j2 = 0; j2 < 8; ++j2) {
        bf16x8 vf = *(const bf16x8*)&Vs[(j2 * 16 + l16) * 64
                                        + ((kk2 * 4 + quad) ^ (l16 & 7)) * 8];
        o[0][j2] = __builtin_amdgcn_mfma_f32_16x16x32_bf16(pf[0][kk2], vf, o[0][j2], 0, 0, 0);
        o[1][j2] = __builtin_amdgcn_mfma_f32_16x16x32_bf16(pf[1][kk2], vf, o[1][j2], 0, 0, 0);
      }
    }
    __builtin_amdgcn_s_setprio(0);
  }

  // write partial L (quads hold disjoint key subsets -> reduce across quads)
  float* opz = op + (size_t)z * SEQ * DIM;
  float* lpz = lp + (size_t)z * HEADS * SEQ + (size_t)h * SEQ;
#pragma unroll
  for (int mt = 0; mt < 2; ++mt) {
    float L = Lr[mt];
    L += __shfl_xor(L, 16);
    L += __shfl_xor(L, 32);
    if (lane < 16) lpz[qbase + mt * 16 + l16] = L;
  }
#pragma unroll
  for (int mt = 0; mt < 2; ++mt) {
#pragma unroll
    for (int j2 = 0; j2 < 8; ++j2) {
      int col = h * HD + j2 * 16 + l16;
#pragma unroll
      for (int r = 0; r < 4; ++r) {
        int row = qbase + mt * 16 + quad * 4 + r;
        opz[(size_t)row * DIM + col] = o[mt][j2][r];
      }
    }
  }
}

// combine nz key-slices: ab = (sum O_z) / (sum L_z), cast to bf16.
__global__ __launch_bounds__(256) void combine_kernel(
    const float* __restrict__ op, const float* __restrict__ lp,
    unsigned short* __restrict__ ab, int nz)
{
  int idx4 = blockIdx.x * 256 + threadIdx.x;      // over SEQ*DIM/4
  int idx = idx4 * 4;
  int row = idx / DIM, col = idx - row * DIM;
  int h = col >> 7;
  float4 o = make_float4(0.f, 0.f, 0.f, 0.f);
  float l = 0.f;
  for (int z = 0; z < nz; ++z) {
    float4 v = *(const float4*)(op + (size_t)z * SEQ * DIM + idx);
    o.x += v.x; o.y += v.y; o.z += v.z; o.w += v.w;
    l += lp[(size_t)z * HEADS * SEQ + (size_t)h * SEQ + row];
  }
  float inv = 1.0f / l;
  union { unsigned short h4[4]; uint2 u; } pk;
  pk.h4[0] = f2b(o.x * inv);
  pk.h4[1] = f2b(o.y * inv);
  pk.h4[2] = f2b(o.z * inv);
  pk.h4[3] = f2b(o.w * inv);
  *(uint2*)&ab[idx] = pk.u;
}

extern "C" void kernel_launch(void* const* d_in, const int* in_sizes, int n_in,
                              void* d_out, int out_size, void* d_ws, size_t ws_size,
                              hipStream_t stream) {
  const int NX = SEQ * DIM, NW = DIM * DIM, NB = DIM, NF = SEQ * 64;

  char* w = (char*)d_ws;
  size_t off = 0;
  int* flag = (int*)(w + off);              off += 256;
  unsigned short* xb  = (unsigned short*)(w + off); off += (size_t)NX * 2;
  unsigned short* Wqb = (unsigned short*)(w + off); off += (size_t)NW * 2;
  unsigned short* Wkb = (unsigned short*)(w + off); off += (size_t)NW * 2;
  unsigned short* Wvb = (unsigned short*)(w + off); off += (size_t)NW * 2;
  unsigned short* Wob = (unsigned short*)(w + off); off += (size_t)NW * 2;
  unsigned short* bqb = (unsigned short*)(w + off); off += 4096;
  unsigned short* bkb = (unsigned short*)(w + off); off += 4096;
  unsigned short* bvb = (unsigned short*)(w + off); off += 4096;
  unsigned short* bob = (unsigned short*)(w + off); off += 4096;
  unsigned short* gqb = (unsigned short*)(w + off); off += 4096;
  unsigned short* gkb = (unsigned short*)(w + off); off += 4096;
  float2* freqcs = (float2*)(w + off);      off += (size_t)NF * 8;
  unsigned short* qb = (unsigned short*)(w + off); off += (size_t)NX * 2;
  unsigned short* kb = (unsigned short*)(w + off); off += (size_t)NX * 2;
  unsigned short* vt = (unsigned short*)(w + off); off += (size_t)NX * 2;
  unsigned short* ab = (unsigned short*)(w + off); off += (size_t)NX * 2;
  float* op = (float*)(w + off);            // nz * NX floats
  float* lp;

  // key-split factor nz=2: grid 768 blocks = 3 resident blocks/CU x 256 CUs.
  int nz = 2;
  size_t need2 = off + (size_t)2 * NX * 4 + (size_t)2 * HEADS * SEQ * 4;
  if (ws_size < need2) {
    signal_kernel<<<1, 64, 0, stream>>>((float*)d_out);
    return;
  }
  lp = (float*)(w + off + (size_t)nz * NX * 4);

  // Host-side dtype resolution from in_sizes (strict, with safe fallback).
  int dt = -1;
  if ((long long)in_sizes[0] == (long long)NX * 2 &&
      (long long)in_sizes[2] == (long long)NW * 2) dt = 0;
  else if ((long long)in_sizes[0] == (long long)NX * 4 &&
           (long long)in_sizes[2] == (long long)NW * 4) dt = 1;

  if (dt < 0)
    detect_kernel<<<1, 256, 0, stream>>>((const unsigned int*)d_in[0], flag);

  const int CT = 256;
  auto cgrid = [](int n) { int g = (n + 255) / 256; return g > 4096 ? 4096 : g; };

  // bf16-known: inputs are readable as bf16 directly -- skip the big copy.
  const unsigned short* xg  = xb;
  const unsigned short* Wqg = Wqb, *Wkg = Wkb, *Wvg = Wvb, *Wog = Wob;
  const unsigned short* bqg = bqb, *bkg = bkb, *bvg = bvb, *bog = bob;
  const unsigned short* gqg = gqb, *gkg = gkb;
  if (dt == 0) {
    xg  = (const unsigned short*)d_in[0];
    Wqg = (const unsigned short*)d_in[2];
    Wkg = (const unsigned short*)d_in[4];
    Wvg = (const unsigned short*)d_in[6];
    Wog = (const unsigned short*)d_in[8];
    bqg = (const unsigned short*)d_in[3];
    bkg = (const unsigned short*)d_in[5];
    bvg = (const unsigned short*)d_in[7];
    bog = (const unsigned short*)d_in[9];
    gqg = (const unsigned short*)d_in[10];
    gkg = (const unsigned short*)d_in[11];
  } else {
    convert_big_kernel<<<dim3(cgrid(NW / 4), 5), CT, 0, stream>>>(
        d_in[0], d_in[2], d_in[4], d_in[6], d_in[8],
        xb, Wqb, Wkb, Wvb, Wob, NX / 4, NW / 4, dt, flag);
  }
  convert_small_kernel<<<dim3(cgrid(NF), 7), CT, 0, stream>>>(
      d_in[3], d_in[5], d_in[7], d_in[9], d_in[10], d_in[11], d_in[1],
      bqb, bkb, bvb, bob, gqb, gkb, freqcs, NB, NF, dt, flag);

  qkv_gemm_kernel<<<dim3(DIM / 128, SEQ / 64, 3), 256, 0, stream>>>(
      xg, Wqg, bqg, Wkg, bkg, Wvg, bvg, qb, kb, vt);
  norm_rope_kernel<<<dim3(SEQ, 2), 256, 0, stream>>>(qb, kb, gqg, gkg, freqcs);
  attn_kernel<<<dim3(SEQ / 128, HEADS, nz), 256, 0, stream>>>(
      qb, kb, vt, op, lp, SEQ / nz, (SEQ / 128) * HEADS * nz);
  combine_kernel<<<NX / 1024, 256, 0, stream>>>(op, lp, ab, nz);
  out_gemm_kernel<<<dim3(DIM / 128, SEQ / 64), 256, 0, stream>>>(
      ab, Wog, bog, d_out, dt, flag);
}